// Round 8
// baseline (1778.711 us; speedup 1.0000x reference)
//
#include <hip/hip_runtime.h>
#include <math.h>

// ---------------- device helpers ----------------

__device__ __forceinline__ float elu_f(float x) {
    return x > 0.f ? x : expm1f(x);
}

// ---------------- node MLP ----------------

__global__ void mlp_kernel(const float* __restrict__ x,
                           const float* __restrict__ A, const float* __restrict__ ab,
                           const float* __restrict__ B, const float* __restrict__ bb,
                           float* __restrict__ out, int n) {
    __shared__ float sA[23 * 23], sB[23 * 23], sa[23], sb[23];
    for (int t = threadIdx.x; t < 23 * 23; t += blockDim.x) { sA[t] = A[t]; sB[t] = B[t]; }
    if (threadIdx.x < 23) { sa[threadIdx.x] = ab[threadIdx.x]; sb[threadIdx.x] = bb[threadIdx.x]; }
    __syncthreads();
    int i = blockIdx.x * blockDim.x + threadIdx.x;
    if (i >= n) return;
    float xi[23], h1[23];
    #pragma unroll
    for (int j = 0; j < 23; j++) xi[j] = x[(size_t)i * 23 + j];
    #pragma unroll
    for (int o = 0; o < 23; o++) {
        float acc = sa[o];
        #pragma unroll
        for (int j = 0; j < 23; j++) acc = fmaf(xi[j], sA[j * 23 + o], acc);
        h1[o] = elu_f(acc);
    }
    #pragma unroll
    for (int o = 0; o < 23; o++) {
        float acc = sb[o];
        #pragma unroll
        for (int j = 0; j < 23; j++) acc = fmaf(h1[j], sB[j * 23 + o], acc);
        out[(size_t)i * 23 + o] = elu_f(acc);
    }
}

// ---------------- register-tiled multi-output projection (GEMM) ----------------
// Mats KM,VM form the kv pair: thread t<OUTW/4 computes k cols [4t..4t+3] AND the
// matching v cols -> float4 pair-stores into channel-interleaved kv rows
// [(k_c,v_c) for c in 0..OUTW). Remaining mats: row-major float4 stores.
template<int IN, int Kc, int OUTW, int M, int TY, int KM, int VM>
__global__ void proj_tiled_kernel(const float* __restrict__ in, int n,
    const float* __restrict__ W0, const float* __restrict__ b0,
    const float* __restrict__ W1, const float* __restrict__ b1,
    const float* __restrict__ W2, const float* __restrict__ b2,
    const float* __restrict__ W3, const float* __restrict__ b3,
    float* __restrict__ kvout,
    float* __restrict__ r0, float* __restrict__ r1,
    float* __restrict__ r2, float* __restrict__ r3) {
    constexpr int WTOT = M * OUTW;
    constexpr int CG   = WTOT / 8;
    constexpr int BN   = TY * 4;
    constexpr int SAW  = BN + 4;
    constexpr int NT   = CG * TY;
    constexpr int PT   = OUTW / 4;          // kv-pair threads
    static_assert(IN % Kc == 0, "Kc divides IN");
    __shared__ float sA[Kc][SAW];
    __shared__ float sB[Kc][WTOT];

    const int tid = threadIdx.x;
    const int tx = tid % CG;
    const int ty = tid / CG;
    const int node0 = blockIdx.x * BN;

    int colA, colB; bool pairkv; int chan0 = 0;
    if (tx < PT) {
        pairkv = true; chan0 = 4 * tx;
        colA = KM * OUTW + chan0;
        colB = VM * OUTW + chan0;
    } else {
        pairkv = false;
        int u = 8 * (tx - PT);
        auto remap = [&](int uu) {
            int ri = uu / OUTW, cc = uu - ri * OUTW;
            int cnt = 0, mat = 0;
            for (int mm = 0; mm < M; mm++) {
                if (mm == KM || mm == VM) continue;
                if (cnt == ri) { mat = mm; break; }
                cnt++;
            }
            return mat * OUTW + cc;
        };
        colA = remap(u); colB = remap(u + 4);
    }
    const int matA = colA / OUTW, ccA = colA % OUTW;
    const int matB = colB / OUTW, ccB = colB % OUTW;
    const float* bA = (matA == 0 ? b0 : matA == 1 ? b1 : matA == 2 ? b2 : b3);
    const float* bB = (matB == 0 ? b0 : matB == 1 ? b1 : matB == 2 ? b2 : b3);

    float acc[4][8];
    #pragma unroll
    for (int i = 0; i < 4; i++) {
        #pragma unroll
        for (int c = 0; c < 4; c++) { acc[i][c] = bA[ccA + c]; acc[i][4 + c] = bB[ccB + c]; }
    }

    for (int k0 = 0; k0 < IN; k0 += Kc) {
        for (int t = tid; t < Kc * BN; t += NT) {
            int j = t / BN, nn = t - j * BN;
            int g = node0 + nn;
            sA[j][nn] = (g < n) ? in[(size_t)g * IN + k0 + j] : 0.f;
        }
        for (int t = tid; t < Kc * WTOT; t += NT) {
            int j = t / WTOT, c = t - j * WTOT;
            int m = c / OUTW, cm = c - m * OUTW;
            const float* Wp = (m == 0 ? W0 : m == 1 ? W1 : m == 2 ? W2 : W3);
            sB[j][c] = Wp[(size_t)(k0 + j) * OUTW + cm];
        }
        __syncthreads();
        #pragma unroll 8
        for (int j = 0; j < Kc; j++) {
            float4 a  = *(const float4*)&sA[j][ty * 4];
            float4 v0 = *(const float4*)&sB[j][colA];
            float4 v1 = *(const float4*)&sB[j][colB];
            float av[4] = {a.x, a.y, a.z, a.w};
            float bv[8] = {v0.x, v0.y, v0.z, v0.w, v1.x, v1.y, v1.z, v1.w};
            #pragma unroll
            for (int i = 0; i < 4; i++)
                #pragma unroll
                for (int c = 0; c < 8; c++)
                    acc[i][c] = fmaf(av[i], bv[c], acc[i][c]);
        }
        __syncthreads();
    }

    #pragma unroll
    for (int i = 0; i < 4; i++) {
        int g = node0 + ty * 4 + i;
        if (g >= n) continue;
        if (pairkv) {
            float* kp = kvout + (size_t)g * (2 * OUTW) + 2 * chan0;
            *(float4*)(kp + 0) = make_float4(acc[i][0], acc[i][4], acc[i][1], acc[i][5]);
            *(float4*)(kp + 4) = make_float4(acc[i][2], acc[i][6], acc[i][3], acc[i][7]);
        } else {
            float* rA = (matA == 0 ? r0 : matA == 1 ? r1 : matA == 2 ? r2 : r3);
            float* rB = (matB == 0 ? r0 : matB == 1 ? r1 : matB == 2 ? r2 : r3);
            *(float4*)(rA + (size_t)g * OUTW + ccA) = make_float4(acc[i][0], acc[i][1], acc[i][2], acc[i][3]);
            *(float4*)(rB + (size_t)g * OUTW + ccB) = make_float4(acc[i][4], acc[i][5], acc[i][6], acc[i][7]);
        }
    }
}

// ---------------- CSR build ----------------

__global__ void zero2_kernel(int* __restrict__ a, int* __restrict__ b, int n) {
    int i = blockIdx.x * blockDim.x + threadIdx.x;
    if (i < n) { a[i] = 0; b[i] = 0; }
}

__global__ void count_kernel(const int* __restrict__ dst, int* __restrict__ cnt, int nE) {
    int e = blockIdx.x * blockDim.x + threadIdx.x;
    if (e < nE) atomicAdd(&cnt[dst[e]], 1);
}

__global__ void scan_block_kernel(int* __restrict__ cnt, int* __restrict__ bsum, int n) {
    __shared__ int sdat[256];
    int i = blockIdx.x * 256 + threadIdx.x;
    int v = (i < n) ? cnt[i] : 0;
    sdat[threadIdx.x] = v;
    __syncthreads();
    for (int off = 1; off < 256; off <<= 1) {
        int t = (threadIdx.x >= (unsigned)off) ? sdat[threadIdx.x - off] : 0;
        __syncthreads();
        sdat[threadIdx.x] += t;
        __syncthreads();
    }
    if (i < n) cnt[i] = sdat[threadIdx.x] - v;
    if (threadIdx.x == 255) bsum[blockIdx.x] = sdat[255];
}

__global__ void scan_bsum_kernel(int* __restrict__ bsum, int nb) {
    __shared__ int s[1024];
    int i = threadIdx.x;
    int v = (i < nb) ? bsum[i] : 0;
    s[i] = v;
    __syncthreads();
    for (int off = 1; off < 1024; off <<= 1) {
        int t = (i >= off) ? s[i - off] : 0;
        __syncthreads();
        s[i] += t;
        __syncthreads();
    }
    if (i < nb) bsum[i] = s[i] - v;
}

__global__ void finalize_rp_kernel(const int* __restrict__ cnt, const int* __restrict__ bsum,
                                   int* __restrict__ rp, int n, int nE) {
    int i = blockIdx.x * blockDim.x + threadIdx.x;
    if (i < n) rp[i] = cnt[i] + bsum[i >> 8];
    if (i == n) rp[n] = nE;
}

__global__ void scatter_kernel(const int* __restrict__ src, const int* __restrict__ dst,
                               const int* __restrict__ rp, int* __restrict__ cur,
                               int* __restrict__ srcS, int* __restrict__ eidS, int nE) {
    int e = blockIdx.x * blockDim.x + threadIdx.x;
    if (e >= nE) return;
    int d = dst[e];
    int pos = rp[d] + atomicAdd(&cur[d], 1);
    srcS[pos] = src[e];
    eidS[pos] = e;
}

// ---------------- fused TransformerConv: one wave per TWO dst nodes ----------------
// kv: channel-pair interleaved fp32 [n][HC][2] = [(k_c,v_c)...]; skip pre-stored in out.
// Two independent edge streams per wave -> 2x memory-level parallelism.
template<int IN, int C, bool QMAT, bool DOELU>
__global__ void conv_fused2_kernel(const float* __restrict__ feat,
                                   const float* __restrict__ Wq, const float* __restrict__ qb,
                                   const float* __restrict__ kv,
                                   const float* __restrict__ qmat,
                                   const float* __restrict__ ea, const float* __restrict__ We,
                                   const int* __restrict__ rp, const int* __restrict__ srcS,
                                   const int* __restrict__ eidS,
                                   float* __restrict__ out, int n, float scale) {
    constexpr int HC = 8 * C;
    constexpr int CPL = HC / 64;
    constexpr int KVROW = 2 * HC;
    const int lane = threadIdx.x & 63;
    const int w = blockIdx.x * (blockDim.x >> 6) + (threadIdx.x >> 6);
    const int d0 = 2 * w;
    if (d0 >= n) return;
    const bool has1 = (d0 + 1) < n;
    const int ch0 = lane * CPL;

    float we[7][CPL];
    #pragma unroll
    for (int j = 0; j < 7; j++)
        #pragma unroll
        for (int c = 0; c < CPL; c++) we[j][c] = We[j * HC + ch0 + c];

    float* op0 = out + (size_t)d0 * HC + ch0;
    float* op1 = op0 + HC;
    float sk0[CPL], sk1[CPL], q0[CPL], q1[CPL];
    #pragma unroll
    for (int c = 0; c < CPL; c++) sk0[c] = op0[c];
    if (has1) {
        #pragma unroll
        for (int c = 0; c < CPL; c++) sk1[c] = op1[c];
    }
    if constexpr (QMAT) {
        const float* qp0 = qmat + (size_t)d0 * HC + ch0;
        #pragma unroll
        for (int c = 0; c < CPL; c++) q0[c] = qp0[c];
        if (has1) {
            const float* qp1 = qp0 + HC;
            #pragma unroll
            for (int c = 0; c < CPL; c++) q1[c] = qp1[c];
        }
    } else {
        #pragma unroll
        for (int c = 0; c < CPL; c++) { q0[c] = qb[ch0 + c]; q1[c] = qb[ch0 + c]; }
        const float* fd0 = feat + (size_t)d0 * IN;
        const float* fd1 = fd0 + IN;
        for (int j = 0; j < IN; j++) {
            float f0 = fd0[j];
            float f1 = has1 ? fd1[j] : 0.f;
            #pragma unroll
            for (int c = 0; c < CPL; c++) {
                float wv = Wq[(size_t)j * HC + ch0 + c];
                q0[c] = fmaf(f0, wv, q0[c]);
                q1[c] = fmaf(f1, wv, q1[c]);
            }
        }
    }

    auto loadEdge = [&](int p, float* kc, float* vc, float* ev) {
        int s = srcS[p], eid = eidS[p];
        const float* pb = kv + (size_t)s * KVROW + 2 * ch0;
        #pragma unroll
        for (int c = 0; c < CPL; c++) {
            float2 t = *(const float2*)(pb + 2 * c);
            kc[c] = t.x; vc[c] = t.y;
        }
        const float* ep = ea + (size_t)eid * 7;
        #pragma unroll
        for (int j = 0; j < 7; j++) ev[j] = ep[j];
    };
    auto step = [&](const float* qv, float& m, float& l, float* accv,
                    const float* kc, const float* vc, const float* ev) {
        float part = 0.f, vv[CPL];
        #pragma unroll
        for (int c = 0; c < CPL; c++) {
            float ec = 0.f;
            #pragma unroll
            for (int j = 0; j < 7; j++) ec = fmaf(ev[j], we[j][c], ec);
            part = fmaf(qv[c], kc[c] + ec, part);
            vv[c] = vc[c] + ec;
        }
        part += __shfl_xor(part, 1);
        part += __shfl_xor(part, 2);
        part += __shfl_xor(part, 4);
        float z = part * scale;
        float mn = fmaxf(m, z);
        float rs = expf(m - mn);
        float pw = expf(z - mn);
        l = l * rs + pw;
        #pragma unroll
        for (int c = 0; c < CPL; c++) accv[c] = fmaf(accv[c], rs, pw * vv[c]);
        m = mn;
    };

    float m0 = -INFINITY, l0 = 0.f, acc0[CPL];
    float m1 = -INFINITY, l1 = 0.f, acc1[CPL];
    #pragma unroll
    for (int c = 0; c < CPL; c++) { acc0[c] = 0.f; acc1[c] = 0.f; }

    int a = rp[d0], aE = rp[d0 + 1];
    int b = has1 ? aE : 0, bE = has1 ? rp[d0 + 2] : 0;

    float kA[CPL], vA[CPL], eA[7], kB[CPL], vB[CPL], eB[7];
    if (a < aE) loadEdge(a, kA, vA, eA);
    if (b < bE) loadEdge(b, kB, vB, eB);

    while (a < aE || b < bE) {
        float kA2[CPL], vA2[CPL], eA2[7], kB2[CPL], vB2[CPL], eB2[7];
        bool nA = (a + 1) < aE, nB = (b + 1) < bE;
        if (nA) loadEdge(a + 1, kA2, vA2, eA2);
        if (nB) loadEdge(b + 1, kB2, vB2, eB2);
        if (a < aE) { step(q0, m0, l0, acc0, kA, vA, eA); a++; }
        if (b < bE) { step(q1, m1, l1, acc1, kB, vB, eB); b++; }
        if (nA) {
            #pragma unroll
            for (int c = 0; c < CPL; c++) { kA[c] = kA2[c]; vA[c] = vA2[c]; }
            #pragma unroll
            for (int j = 0; j < 7; j++) eA[j] = eA2[j];
        }
        if (nB) {
            #pragma unroll
            for (int c = 0; c < CPL; c++) { kB[c] = kB2[c]; vB[c] = vB2[c]; }
            #pragma unroll
            for (int j = 0; j < 7; j++) eB[j] = eB2[j];
        }
    }

    float il0 = (l0 > 0.f) ? 1.f / l0 : 0.f;
    #pragma unroll
    for (int c = 0; c < CPL; c++) {
        float r = sk0[c] + acc0[c] * il0;
        op0[c] = DOELU ? elu_f(r) : r;
    }
    if (has1) {
        float il1 = (l1 > 0.f) ? 1.f / l1 : 0.f;
        #pragma unroll
        for (int c = 0; c < CPL; c++) {
            float r = sk1[c] + acc1[c] * il1;
            op1[c] = DOELU ? elu_f(r) : r;
        }
    }
}

// ---------------- head ----------------
__global__ void head_kernel(const float* __restrict__ h, const float* __restrict__ W1,
                            const float* __restrict__ b1, const float* __restrict__ W2,
                            const float* __restrict__ b2, float* __restrict__ out, int n) {
    __shared__ float sW1[64 * 20], sb1[20], sW2[20], sb2;
    for (int t = threadIdx.x; t < 64 * 20; t += blockDim.x) sW1[t] = W1[t];
    if (threadIdx.x < 20) { sb1[threadIdx.x] = b1[threadIdx.x]; sW2[threadIdx.x] = W2[threadIdx.x]; }
    if (threadIdx.x == 0) sb2 = b2[0];
    __syncthreads();
    int i = blockIdx.x * blockDim.x + threadIdx.x;
    if (i >= n) return;
    float hv[64];
    const float* hp = h + (size_t)i * 64;
    #pragma unroll
    for (int j = 0; j < 64; j++) hv[j] = elu_f(hp[j]);
    float acc2 = sb2;
    for (int o = 0; o < 20; o++) {
        float a = sb1[o];
        #pragma unroll
        for (int j = 0; j < 64; j++) a = fmaf(hv[j], sW1[j * 20 + o], a);
        acc2 = fmaf(elu_f(a), sW2[o], acc2);
    }
    out[i] = acc2;
}

__global__ void zero_out_kernel(float* __restrict__ out, int n) {
    int i = blockIdx.x * blockDim.x + threadIdx.x;
    if (i < n) out[i] = 0.f;
}

// ---------------- launcher ----------------

extern "C" void kernel_launch(void* const* d_in, const int* in_sizes, int n_in,
                              void* d_out, int out_size, void* d_ws, size_t ws_size,
                              hipStream_t stream) {
    const float* x   = (const float*)d_in[0];
    const int*   ei  = (const int*)d_in[1];
    const float* ea  = (const float*)d_in[2];
    const float* Aw  = (const float*)d_in[3];
    const float* Ab  = (const float*)d_in[4];
    const float* Bw  = (const float*)d_in[5];
    const float* Bb  = (const float*)d_in[6];
    const float* q1w = (const float*)d_in[7];  const float* q1b = (const float*)d_in[8];
    const float* k1w = (const float*)d_in[9];  const float* k1b = (const float*)d_in[10];
    const float* v1w = (const float*)d_in[11]; const float* v1b = (const float*)d_in[12];
    const float* e1w = (const float*)d_in[13];
    const float* s1w = (const float*)d_in[14]; const float* s1b = (const float*)d_in[15];
    const float* q2w = (const float*)d_in[16]; const float* q2b = (const float*)d_in[17];
    const float* k2w = (const float*)d_in[18]; const float* k2b = (const float*)d_in[19];
    const float* v2w = (const float*)d_in[20]; const float* v2b = (const float*)d_in[21];
    const float* e2w = (const float*)d_in[22];
    const float* s2w = (const float*)d_in[23]; const float* s2b = (const float*)d_in[24];
    const float* l1w = (const float*)d_in[25]; const float* l1b = (const float*)d_in[26];
    const float* l2w = (const float*)d_in[27]; const float* l2b = (const float*)d_in[28];

    const int n  = in_sizes[0] / 23;
    const int nE = in_sizes[1] / 2;
    const int* src = ei;
    const int* dst = ei + nE;
    float* out = (float*)d_out;
    const int B = 256;
    const int nb = (n + 255) / 256;

    // ---- workspace layout (float units); total = 599n floats + ints ≈ 247.2 MB ----
    size_t fl_h1 = ((size_t)n * 23 + 3) & ~(size_t)3;
    size_t fl_o1 = (size_t)n * 192;
    size_t fl_kv = (size_t)n * 384;   // kv1; conv2 reuses: kv2(128n)+q2(64n)+o2(64n)
    size_t ints_total = ((size_t)n + 1) + n + n + 1024 + (size_t)nE + (size_t)nE;
    size_t need_bytes = (fl_h1 + fl_o1 + fl_kv) * 4 + ints_total * 4;

    if (ws_size < need_bytes || nb > 1024) {
        zero_out_kernel<<<(out_size + B - 1) / B, B, 0, stream>>>(out, out_size);
        return;
    }

    float* ws = (float*)d_ws;
    size_t off = 0;
    float* h1    = ws + off; off += fl_h1;
    float* o1    = ws + off; off += fl_o1;
    float* kvreg = ws + off; off += fl_kv;
    int* ip = (int*)(ws + off);
    int* rp   = ip; ip += (size_t)n + 1;
    int* cnt  = ip; ip += n;
    int* cur  = ip; ip += n;
    int* bsum = ip; ip += 1024;
    int* srcS = ip; ip += nE;
    int* eidS = ip; ip += nE;

    float* kv1   = kvreg;                          // n*384 floats, channel-pair interleaved
    float* kv2   = kvreg;                          // n*128 floats (reuse after conv1)
    float* q2buf = kvreg + (size_t)n * 128;        // n*64
    float* o2    = kvreg + (size_t)n * 192;        // n*64

    const float sc1 = 1.0f / sqrtf(24.0f);
    const float sc2 = 1.0f / sqrtf(8.0f);
    const float* np = nullptr;
    float* npw = nullptr;

    // ---- CSR build ----
    zero2_kernel<<<(n + B - 1) / B, B, 0, stream>>>(cnt, cur, n);
    count_kernel<<<(nE + B - 1) / B, B, 0, stream>>>(dst, cnt, nE);
    scan_block_kernel<<<nb, 256, 0, stream>>>(cnt, bsum, n);
    scan_bsum_kernel<<<1, 1024, 0, stream>>>(bsum, nb);
    finalize_rp_kernel<<<(n + 1 + B - 1) / B, B, 0, stream>>>(cnt, bsum, rp, n, nE);
    scatter_kernel<<<(nE + B - 1) / B, B, 0, stream>>>(src, dst, rp, cur, srcS, eidS, nE);

    // ---- node MLP ----
    mlp_kernel<<<(n + B - 1) / B, B, 0, stream>>>(x, Aw, Ab, Bw, Bb, h1, n);

    // ---- conv1: k,v -> kv1 (pair), skip -> o1; fused dual-dst edge phase ----
    proj_tiled_kernel<23, 23, 192, 3, 8, 0, 1><<<(n + 31) / 32, 576, 0, stream>>>(
        h1, n, k1w, k1b, v1w, v1b, s1w, s1b, np, np,
        kv1, npw, npw, o1, npw);
    conv_fused2_kernel<23, 24, false, true><<<(n + 7) / 8, 256, 0, stream>>>(
        h1, q1w, q1b, kv1, np, ea, e1w, rp, srcS, eidS, o1, n, sc1);

    // ---- conv2: q->q2buf, k,v->kv2 (pair), skip->o2; fused dual-dst edge phase ----
    proj_tiled_kernel<192, 32, 64, 4, 16, 1, 2><<<(n + 63) / 64, 512, 0, stream>>>(
        o1, n, q2w, q2b, k2w, k2b, v2w, v2b, s2w, s2b,
        kv2, q2buf, npw, npw, o2);
    conv_fused2_kernel<192, 8, true, false><<<(n + 7) / 8, 256, 0, stream>>>(
        o1, q2w, q2b, kv2, q2buf, ea, e2w, rp, srcS, eidS, o2, n, sc2);

    // ---- head ----
    head_kernel<<<(n + B - 1) / B, B, 0, stream>>>(o2, l1w, l1b, l2w, l2b, out, n);
}

// Round 9
// 1301.548 us; speedup vs baseline: 1.3666x; 1.3666x over previous
//
#include <hip/hip_runtime.h>
#include <math.h>

// ---------------- device helpers ----------------

__device__ __forceinline__ float elu_f(float x) {
    return x > 0.f ? x : expm1f(x);
}

// ---------------- node MLP ----------------

__global__ void mlp_kernel(const float* __restrict__ x,
                           const float* __restrict__ A, const float* __restrict__ ab,
                           const float* __restrict__ B, const float* __restrict__ bb,
                           float* __restrict__ out, int n) {
    __shared__ float sA[23 * 23], sB[23 * 23], sa[23], sb[23];
    for (int t = threadIdx.x; t < 23 * 23; t += blockDim.x) { sA[t] = A[t]; sB[t] = B[t]; }
    if (threadIdx.x < 23) { sa[threadIdx.x] = ab[threadIdx.x]; sb[threadIdx.x] = bb[threadIdx.x]; }
    __syncthreads();
    int i = blockIdx.x * blockDim.x + threadIdx.x;
    if (i >= n) return;
    float xi[23], h1[23];
    #pragma unroll
    for (int j = 0; j < 23; j++) xi[j] = x[(size_t)i * 23 + j];
    #pragma unroll
    for (int o = 0; o < 23; o++) {
        float acc = sa[o];
        #pragma unroll
        for (int j = 0; j < 23; j++) acc = fmaf(xi[j], sA[j * 23 + o], acc);
        h1[o] = elu_f(acc);
    }
    #pragma unroll
    for (int o = 0; o < 23; o++) {
        float acc = sb[o];
        #pragma unroll
        for (int j = 0; j < 23; j++) acc = fmaf(h1[j], sB[j * 23 + o], acc);
        out[(size_t)i * 23 + o] = elu_f(acc);
    }
}

// ---------------- register-tiled multi-output projection (GEMM) ----------------
// Mats KM,VM form the kv pair: thread t<OUTW/4 computes k cols [4t..4t+3] AND the
// matching v cols -> float4 pair-stores into channel-interleaved kv rows
// [(k_c,v_c) for c in 0..OUTW). Remaining mats: row-major float4 stores.
template<int IN, int Kc, int OUTW, int M, int TY, int KM, int VM>
__global__ void proj_tiled_kernel(const float* __restrict__ in, int n,
    const float* __restrict__ W0, const float* __restrict__ b0,
    const float* __restrict__ W1, const float* __restrict__ b1,
    const float* __restrict__ W2, const float* __restrict__ b2,
    const float* __restrict__ W3, const float* __restrict__ b3,
    float* __restrict__ kvout,
    float* __restrict__ r0, float* __restrict__ r1,
    float* __restrict__ r2, float* __restrict__ r3) {
    constexpr int WTOT = M * OUTW;
    constexpr int CG   = WTOT / 8;
    constexpr int BN   = TY * 4;
    constexpr int SAW  = BN + 4;
    constexpr int NT   = CG * TY;
    constexpr int PT   = OUTW / 4;          // kv-pair threads
    static_assert(IN % Kc == 0, "Kc divides IN");
    __shared__ float sA[Kc][SAW];
    __shared__ float sB[Kc][WTOT];

    const int tid = threadIdx.x;
    const int tx = tid % CG;
    const int ty = tid / CG;
    const int node0 = blockIdx.x * BN;

    int colA, colB; bool pairkv; int chan0 = 0;
    if (tx < PT) {
        pairkv = true; chan0 = 4 * tx;
        colA = KM * OUTW + chan0;
        colB = VM * OUTW + chan0;
    } else {
        pairkv = false;
        int u = 8 * (tx - PT);
        auto remap = [&](int uu) {
            int ri = uu / OUTW, cc = uu - ri * OUTW;
            int cnt = 0, mat = 0;
            for (int mm = 0; mm < M; mm++) {
                if (mm == KM || mm == VM) continue;
                if (cnt == ri) { mat = mm; break; }
                cnt++;
            }
            return mat * OUTW + cc;
        };
        colA = remap(u); colB = remap(u + 4);
    }
    const int matA = colA / OUTW, ccA = colA % OUTW;
    const int matB = colB / OUTW, ccB = colB % OUTW;
    const float* bA = (matA == 0 ? b0 : matA == 1 ? b1 : matA == 2 ? b2 : b3);
    const float* bB = (matB == 0 ? b0 : matB == 1 ? b1 : matB == 2 ? b2 : b3);

    float acc[4][8];
    #pragma unroll
    for (int i = 0; i < 4; i++) {
        #pragma unroll
        for (int c = 0; c < 4; c++) { acc[i][c] = bA[ccA + c]; acc[i][4 + c] = bB[ccB + c]; }
    }

    for (int k0 = 0; k0 < IN; k0 += Kc) {
        for (int t = tid; t < Kc * BN; t += NT) {
            int j = t / BN, nn = t - j * BN;
            int g = node0 + nn;
            sA[j][nn] = (g < n) ? in[(size_t)g * IN + k0 + j] : 0.f;
        }
        for (int t = tid; t < Kc * WTOT; t += NT) {
            int j = t / WTOT, c = t - j * WTOT;
            int m = c / OUTW, cm = c - m * OUTW;
            const float* Wp = (m == 0 ? W0 : m == 1 ? W1 : m == 2 ? W2 : W3);
            sB[j][c] = Wp[(size_t)(k0 + j) * OUTW + cm];
        }
        __syncthreads();
        #pragma unroll 8
        for (int j = 0; j < Kc; j++) {
            float4 a  = *(const float4*)&sA[j][ty * 4];
            float4 v0 = *(const float4*)&sB[j][colA];
            float4 v1 = *(const float4*)&sB[j][colB];
            float av[4] = {a.x, a.y, a.z, a.w};
            float bv[8] = {v0.x, v0.y, v0.z, v0.w, v1.x, v1.y, v1.z, v1.w};
            #pragma unroll
            for (int i = 0; i < 4; i++)
                #pragma unroll
                for (int c = 0; c < 8; c++)
                    acc[i][c] = fmaf(av[i], bv[c], acc[i][c]);
        }
        __syncthreads();
    }

    #pragma unroll
    for (int i = 0; i < 4; i++) {
        int g = node0 + ty * 4 + i;
        if (g >= n) continue;
        if (pairkv) {
            float* kp = kvout + (size_t)g * (2 * OUTW) + 2 * chan0;
            *(float4*)(kp + 0) = make_float4(acc[i][0], acc[i][4], acc[i][1], acc[i][5]);
            *(float4*)(kp + 4) = make_float4(acc[i][2], acc[i][6], acc[i][3], acc[i][7]);
        } else {
            float* rA = (matA == 0 ? r0 : matA == 1 ? r1 : matA == 2 ? r2 : r3);
            float* rB = (matB == 0 ? r0 : matB == 1 ? r1 : matB == 2 ? r2 : r3);
            *(float4*)(rA + (size_t)g * OUTW + ccA) = make_float4(acc[i][0], acc[i][1], acc[i][2], acc[i][3]);
            *(float4*)(rB + (size_t)g * OUTW + ccB) = make_float4(acc[i][4], acc[i][5], acc[i][6], acc[i][7]);
        }
    }
}

// ---------------- CSR build ----------------

__global__ void zero2_kernel(int* __restrict__ a, int* __restrict__ b, int n) {
    int i = blockIdx.x * blockDim.x + threadIdx.x;
    if (i < n) { a[i] = 0; b[i] = 0; }
}

__global__ void count_kernel(const int* __restrict__ dst, int* __restrict__ cnt, int nE) {
    int e = blockIdx.x * blockDim.x + threadIdx.x;
    if (e < nE) atomicAdd(&cnt[dst[e]], 1);
}

__global__ void scan_block_kernel(int* __restrict__ cnt, int* __restrict__ bsum, int n) {
    __shared__ int sdat[256];
    int i = blockIdx.x * 256 + threadIdx.x;
    int v = (i < n) ? cnt[i] : 0;
    sdat[threadIdx.x] = v;
    __syncthreads();
    for (int off = 1; off < 256; off <<= 1) {
        int t = (threadIdx.x >= (unsigned)off) ? sdat[threadIdx.x - off] : 0;
        __syncthreads();
        sdat[threadIdx.x] += t;
        __syncthreads();
    }
    if (i < n) cnt[i] = sdat[threadIdx.x] - v;
    if (threadIdx.x == 255) bsum[blockIdx.x] = sdat[255];
}

__global__ void scan_bsum_kernel(int* __restrict__ bsum, int nb) {
    __shared__ int s[1024];
    int i = threadIdx.x;
    int v = (i < nb) ? bsum[i] : 0;
    s[i] = v;
    __syncthreads();
    for (int off = 1; off < 1024; off <<= 1) {
        int t = (i >= off) ? s[i - off] : 0;
        __syncthreads();
        s[i] += t;
        __syncthreads();
    }
    if (i < nb) bsum[i] = s[i] - v;
}

__global__ void finalize_rp_kernel(const int* __restrict__ cnt, const int* __restrict__ bsum,
                                   int* __restrict__ rp, int n, int nE) {
    int i = blockIdx.x * blockDim.x + threadIdx.x;
    if (i < n) rp[i] = cnt[i] + bsum[i >> 8];
    if (i == n) rp[n] = nE;
}

__global__ void scatter_kernel(const int* __restrict__ src, const int* __restrict__ dst,
                               const int* __restrict__ rp, int* __restrict__ cur,
                               int* __restrict__ srcS, int* __restrict__ eidS, int nE) {
    int e = blockIdx.x * blockDim.x + threadIdx.x;
    if (e >= nE) return;
    int d = dst[e];
    int pos = rp[d] + atomicAdd(&cur[d], 1);
    srcS[pos] = src[e];
    eidS[pos] = e;
}

// ---------------- fused TransformerConv (one wave per dst node) ----------------
// kv: channel-pair interleaved fp32 [n][HC][2] = [(k_c,v_c)...]; skip pre-stored in out.
// 2-wide unrolled edge loop, branchless clamped depth-2 prefetch, pairwise
// online-softmax update (odd tail handled via z=-INF -> exp=0 no-op).
template<int IN, int C, bool QMAT, bool DOELU>
__global__ void conv_fused_kernel(const float* __restrict__ feat,
                                  const float* __restrict__ Wq, const float* __restrict__ qb,
                                  const float* __restrict__ kv,
                                  const float* __restrict__ qmat,
                                  const float* __restrict__ ea, const float* __restrict__ We,
                                  const int* __restrict__ rp, const int* __restrict__ srcS,
                                  const int* __restrict__ eidS,
                                  float* __restrict__ out, int n, float scale) {
    constexpr int HC = 8 * C;
    constexpr int CPL = HC / 64;
    constexpr int KVROW = 2 * HC;
    const int lane = threadIdx.x & 63;
    const int d = blockIdx.x * (blockDim.x >> 6) + (threadIdx.x >> 6);
    if (d >= n) return;
    const int ch0 = lane * CPL;

    float we[7][CPL];
    #pragma unroll
    for (int j = 0; j < 7; j++)
        #pragma unroll
        for (int c = 0; c < CPL; c++) we[j][c] = We[j * HC + ch0 + c];

    float* op = out + (size_t)d * HC + ch0;
    float sk[CPL], q[CPL];
    #pragma unroll
    for (int c = 0; c < CPL; c++) sk[c] = op[c];       // pre-stored skip
    if constexpr (QMAT) {
        const float* qp = qmat + (size_t)d * HC + ch0;
        #pragma unroll
        for (int c = 0; c < CPL; c++) q[c] = qp[c];
    } else {
        #pragma unroll
        for (int c = 0; c < CPL; c++) q[c] = qb[ch0 + c];
        const float* fd = feat + (size_t)d * IN;
        for (int j = 0; j < IN; j++) {
            float f = fd[j];
            #pragma unroll
            for (int c = 0; c < CPL; c++)
                q[c] = fmaf(f, Wq[(size_t)j * HC + ch0 + c], q[c]);
        }
    }

    float m = -INFINITY, l = 0.f, acc[CPL];
    #pragma unroll
    for (int c = 0; c < CPL; c++) acc[c] = 0.f;

    const int p0 = rp[d], p1 = rp[d + 1];
    if (p0 < p1) {
        auto loadEdge = [&](int p, float* kc, float* vc, float* ev) {
            int s = srcS[p], eid = eidS[p];
            const float* pb = kv + (size_t)s * KVROW + 2 * ch0;
            #pragma unroll
            for (int c = 0; c < CPL; c++) {
                float2 t = *(const float2*)(pb + 2 * c);
                kc[c] = t.x; vc[c] = t.y;
            }
            const float* ep = ea + (size_t)eid * 7;
            #pragma unroll
            for (int j = 0; j < 7; j++) ev[j] = ep[j];
        };
        // logit+value for one edge (no softmax state update)
        auto logitv = [&](const float* kc, const float* vc, const float* ev, float* vv) {
            float part = 0.f;
            #pragma unroll
            for (int c = 0; c < CPL; c++) {
                float ec = 0.f;
                #pragma unroll
                for (int j = 0; j < 7; j++) ec = fmaf(ev[j], we[j][c], ec);
                part = fmaf(q[c], kc[c] + ec, part);
                vv[c] = vc[c] + ec;
            }
            part += __shfl_xor(part, 1);
            part += __shfl_xor(part, 2);
            part += __shfl_xor(part, 4);
            return part * scale;
        };

        const int pL = p1 - 1;
        float k0a[CPL], v0a[CPL], e0a[7], k1a[CPL], v1a[CPL], e1a[7];
        loadEdge(p0, k0a, v0a, e0a);
        loadEdge((p0 + 1 < p1) ? p0 + 1 : pL, k1a, v1a, e1a);

        for (int p = p0; p < p1; p += 2) {
            float k2a[CPL], v2a[CPL], e2a[7], k3a[CPL], v3a[CPL], e3a[7];
            loadEdge((p + 2 < p1) ? p + 2 : pL, k2a, v2a, e2a);   // branchless prefetch
            loadEdge((p + 3 < p1) ? p + 3 : pL, k3a, v3a, e3a);

            float vv0[CPL], vv1[CPL];
            float z0 = logitv(k0a, v0a, e0a, vv0);
            float z1 = logitv(k1a, v1a, e1a, vv1);
            if (p + 1 >= p1) z1 = -INFINITY;            // odd tail -> no-op

            float mn = fmaxf(m, fmaxf(z0, z1));
            float rs  = expf(m - mn);
            float pw0 = expf(z0 - mn);
            float pw1 = expf(z1 - mn);
            l = fmaf(l, rs, pw0 + pw1);
            #pragma unroll
            for (int c = 0; c < CPL; c++)
                acc[c] = fmaf(acc[c], rs, fmaf(pw0, vv0[c], pw1 * vv1[c]));
            m = mn;

            #pragma unroll
            for (int c = 0; c < CPL; c++) {
                k0a[c] = k2a[c]; v0a[c] = v2a[c];
                k1a[c] = k3a[c]; v1a[c] = v3a[c];
            }
            #pragma unroll
            for (int j = 0; j < 7; j++) { e0a[j] = e2a[j]; e1a[j] = e3a[j]; }
        }
    }
    float invl = (l > 0.f) ? 1.f / l : 0.f;
    #pragma unroll
    for (int c = 0; c < CPL; c++) {
        float r = sk[c] + acc[c] * invl;
        op[c] = DOELU ? elu_f(r) : r;
    }
}

// ---------------- head ----------------
__global__ void head_kernel(const float* __restrict__ h, const float* __restrict__ W1,
                            const float* __restrict__ b1, const float* __restrict__ W2,
                            const float* __restrict__ b2, float* __restrict__ out, int n) {
    __shared__ float sW1[64 * 20], sb1[20], sW2[20], sb2;
    for (int t = threadIdx.x; t < 64 * 20; t += blockDim.x) sW1[t] = W1[t];
    if (threadIdx.x < 20) { sb1[threadIdx.x] = b1[threadIdx.x]; sW2[threadIdx.x] = W2[threadIdx.x]; }
    if (threadIdx.x == 0) sb2 = b2[0];
    __syncthreads();
    int i = blockIdx.x * blockDim.x + threadIdx.x;
    if (i >= n) return;
    float hv[64];
    const float* hp = h + (size_t)i * 64;
    #pragma unroll
    for (int j = 0; j < 64; j++) hv[j] = elu_f(hp[j]);
    float acc2 = sb2;
    for (int o = 0; o < 20; o++) {
        float a = sb1[o];
        #pragma unroll
        for (int j = 0; j < 64; j++) a = fmaf(hv[j], sW1[j * 20 + o], a);
        acc2 = fmaf(elu_f(a), sW2[o], acc2);
    }
    out[i] = acc2;
}

__global__ void zero_out_kernel(float* __restrict__ out, int n) {
    int i = blockIdx.x * blockDim.x + threadIdx.x;
    if (i < n) out[i] = 0.f;
}

// ---------------- launcher ----------------

extern "C" void kernel_launch(void* const* d_in, const int* in_sizes, int n_in,
                              void* d_out, int out_size, void* d_ws, size_t ws_size,
                              hipStream_t stream) {
    const float* x   = (const float*)d_in[0];
    const int*   ei  = (const int*)d_in[1];
    const float* ea  = (const float*)d_in[2];
    const float* Aw  = (const float*)d_in[3];
    const float* Ab  = (const float*)d_in[4];
    const float* Bw  = (const float*)d_in[5];
    const float* Bb  = (const float*)d_in[6];
    const float* q1w = (const float*)d_in[7];  const float* q1b = (const float*)d_in[8];
    const float* k1w = (const float*)d_in[9];  const float* k1b = (const float*)d_in[10];
    const float* v1w = (const float*)d_in[11]; const float* v1b = (const float*)d_in[12];
    const float* e1w = (const float*)d_in[13];
    const float* s1w = (const float*)d_in[14]; const float* s1b = (const float*)d_in[15];
    const float* q2w = (const float*)d_in[16]; const float* q2b = (const float*)d_in[17];
    const float* k2w = (const float*)d_in[18]; const float* k2b = (const float*)d_in[19];
    const float* v2w = (const float*)d_in[20]; const float* v2b = (const float*)d_in[21];
    const float* e2w = (const float*)d_in[22];
    const float* s2w = (const float*)d_in[23]; const float* s2b = (const float*)d_in[24];
    const float* l1w = (const float*)d_in[25]; const float* l1b = (const float*)d_in[26];
    const float* l2w = (const float*)d_in[27]; const float* l2b = (const float*)d_in[28];

    const int n  = in_sizes[0] / 23;
    const int nE = in_sizes[1] / 2;
    const int* src = ei;
    const int* dst = ei + nE;
    float* out = (float*)d_out;
    const int B = 256;
    const int nb = (n + 255) / 256;

    // ---- workspace layout (float units); total = 599n floats + ints ≈ 247.2 MB ----
    size_t fl_h1 = ((size_t)n * 23 + 3) & ~(size_t)3;
    size_t fl_o1 = (size_t)n * 192;
    size_t fl_kv = (size_t)n * 384;   // kv1; conv2 reuses: kv2(128n)+q2(64n)+o2(64n)
    size_t ints_total = ((size_t)n + 1) + n + n + 1024 + (size_t)nE + (size_t)nE;
    size_t need_bytes = (fl_h1 + fl_o1 + fl_kv) * 4 + ints_total * 4;

    if (ws_size < need_bytes || nb > 1024) {
        zero_out_kernel<<<(out_size + B - 1) / B, B, 0, stream>>>(out, out_size);
        return;
    }

    float* ws = (float*)d_ws;
    size_t off = 0;
    float* h1    = ws + off; off += fl_h1;
    float* o1    = ws + off; off += fl_o1;
    float* kvreg = ws + off; off += fl_kv;
    int* ip = (int*)(ws + off);
    int* rp   = ip; ip += (size_t)n + 1;
    int* cnt  = ip; ip += n;
    int* cur  = ip; ip += n;
    int* bsum = ip; ip += 1024;
    int* srcS = ip; ip += nE;
    int* eidS = ip; ip += nE;

    float* kv1   = kvreg;                          // n*384 floats, channel-pair interleaved
    float* kv2   = kvreg;                          // n*128 floats (reuse after conv1)
    float* q2buf = kvreg + (size_t)n * 128;        // n*64
    float* o2    = kvreg + (size_t)n * 192;        // n*64

    const float sc1 = 1.0f / sqrtf(24.0f);
    const float sc2 = 1.0f / sqrtf(8.0f);
    const float* np = nullptr;
    float* npw = nullptr;

    // ---- CSR build ----
    zero2_kernel<<<(n + B - 1) / B, B, 0, stream>>>(cnt, cur, n);
    count_kernel<<<(nE + B - 1) / B, B, 0, stream>>>(dst, cnt, nE);
    scan_block_kernel<<<nb, 256, 0, stream>>>(cnt, bsum, n);
    scan_bsum_kernel<<<1, 1024, 0, stream>>>(bsum, nb);
    finalize_rp_kernel<<<(n + 1 + B - 1) / B, B, 0, stream>>>(cnt, bsum, rp, n, nE);
    scatter_kernel<<<(nE + B - 1) / B, B, 0, stream>>>(src, dst, rp, cur, srcS, eidS, nE);

    // ---- node MLP ----
    mlp_kernel<<<(n + B - 1) / B, B, 0, stream>>>(x, Aw, Ab, Bw, Bb, h1, n);

    // ---- conv1: k,v -> kv1 (pair), skip -> o1; fused edge phase ----
    proj_tiled_kernel<23, 23, 192, 3, 8, 0, 1><<<(n + 31) / 32, 576, 0, stream>>>(
        h1, n, k1w, k1b, v1w, v1b, s1w, s1b, np, np,
        kv1, npw, npw, o1, npw);
    conv_fused_kernel<23, 24, false, true><<<(n + 3) / 4, 256, 0, stream>>>(
        h1, q1w, q1b, kv1, np, ea, e1w, rp, srcS, eidS, o1, n, sc1);

    // ---- conv2: q->q2buf, k,v->kv2 (pair), skip->o2; fused edge phase ----
    proj_tiled_kernel<192, 32, 64, 4, 16, 1, 2><<<(n + 63) / 64, 512, 0, stream>>>(
        o1, n, q2w, q2b, k2w, k2b, v2w, v2b, s2w, s2b,
        kv2, q2buf, npw, npw, o2);
    conv_fused_kernel<192, 8, true, false><<<(n + 3) / 4, 256, 0, stream>>>(
        o1, q2w, q2b, kv2, q2buf, ea, e2w, rp, srcS, eidS, o2, n, sc2);

    // ---- head ----
    head_kernel<<<(n + B - 1) / B, B, 0, stream>>>(o2, l1w, l1b, l2w, l2b, out, n);
}